// Round 14
// baseline (1015.497 us; speedup 1.0000x reference)
//
#include <hip/hip_runtime.h>
#include <hip/hip_bf16.h>

typedef short short8 __attribute__((ext_vector_type(8)));
typedef short short4v __attribute__((ext_vector_type(4)));
typedef float f32x4 __attribute__((ext_vector_type(4)));
typedef __bf16 bf16x8 __attribute__((ext_vector_type(8)));

#define DEVI static __device__ __forceinline__

#if __has_builtin(__builtin_amdgcn_exp2f)
#define EXP2(x) __builtin_amdgcn_exp2f(x)
#else
#define EXP2(x) exp2f(x)
#endif
#if __has_builtin(__builtin_amdgcn_rcpf)
#define RCP(x) __builtin_amdgcn_rcpf(x)
#else
#define RCP(x) (1.0f / (x))
#endif

static constexpr int BB = 256, TT = 512, DIN0 = 40, HH = 128, NCLS = 7;
static constexpr float L2E = 1.44269504088896f;

DEVI short f2b(float x) {
  union { __hip_bfloat16 h; short s; } u;
  u.h = __float2bfloat16(x);
  return u.s;
}
DEVI float b2f(short s) {
  union { unsigned u; float f; } v;
  v.u = ((unsigned)(unsigned short)s) << 16;
  return v.f;
}
DEVI bf16x8 as_bf(short8 s) { return __builtin_bit_cast(bf16x8, s); }

DEVI void bar_lgkm() {
  asm volatile("s_waitcnt lgkmcnt(0)\n\ts_barrier" ::: "memory");
}

// Latency-optimized 1-cell LSTM update: 5 exp2 + 5 rcp, but the 4 gate
// reciprocals are INDEPENDENT (parallel ~40cyc path vs Montgomery's serial
// ~100cyc product chain). Throughput of trans ops proven non-binding
// (R6/R8/R10 nulls). Gates pre-scaled: i,f,o by -log2e; g by 2*log2e.
DEVI void cell1L(float gi, float gf, float gg, float go, float& c, float& h) {
  float si = RCP(1.f + EXP2(fminf(gi, 30.f)));
  float sf = RCP(1.f + EXP2(fminf(gf, 30.f)));
  float gd = RCP(1.f + EXP2(fminf(gg, 30.f)));
  float so = RCP(1.f + EXP2(fminf(go, 30.f)));
  float tg = 1.f - 2.f * gd;
  c = sf * c + si * tg;
  float tc = 1.f - 2.f * RCP(1.f + EXP2(fminf(c * (2.f * L2E), 30.f)));
  h = so * tc;
}

// 2-cell variant for the fused fallback (R8-proven).
DEVI void cell2(float gi0, float gf0, float gg0, float go0,
                float gi1, float gf1, float gg1, float go1,
                float& c0, float& c1, float& h0, float& h1) {
  float d0 = 1.f + EXP2(fminf(gi0, 14.f));
  float d1 = 1.f + EXP2(fminf(gf0, 14.f));
  float d2 = 1.f + EXP2(fminf(gg0, 14.f));
  float d3 = 1.f + EXP2(fminf(go0, 14.f));
  float d4 = 1.f + EXP2(fminf(gi1, 14.f));
  float d5 = 1.f + EXP2(fminf(gf1, 14.f));
  float d6 = 1.f + EXP2(fminf(gg1, 14.f));
  float d7 = 1.f + EXP2(fminf(go1, 14.f));
  float p1 = d0 * d1, p2 = p1 * d2, p3 = p2 * d3, p4 = p3 * d4;
  float p5 = p4 * d5, p6 = p5 * d6, p7 = p6 * d7;
  float R = RCP(p7);
  float r7 = R * p6; R *= d7;
  float r6 = R * p5; R *= d6;
  float r5 = R * p4; R *= d5;
  float r4 = R * p3; R *= d4;
  float r3 = R * p2; R *= d3;
  float r2 = R * p1; R *= d2;
  float r1 = R * d0, r0 = R * d1;
  float tg0 = 1.f - 2.f * r2, tg1 = 1.f - 2.f * r6;
  c0 = r1 * c0 + r0 * tg0;
  c1 = r5 * c1 + r4 * tg1;
  float q0 = 1.f + EXP2(fminf(c0 * (2.f * L2E), 30.f));
  float q1 = 1.f + EXP2(fminf(c1 * (2.f * L2E), 30.f));
  float Rq = RCP(q0 * q1);
  h0 = r3 * (1.f - 2.f * Rq * q1);
  h1 = r7 * (1.f - 2.f * Rq * q0);
}

// Two-stage compaction: move cell (col=c, r) to lane c + 4r (within 16-lane
// group). Only acc values from lanes bcol<4 are consumed.
#define COMPACT4(g, acc, hi2, hi)                       \
  {                                                     \
    float s0 = acc[0], s1 = acc[1], s2 = acc[2], s3 = acc[3]; \
    float t1 = __shfl_xor(s1, 4);                       \
    float t3 = __shfl_xor(s3, 4);                       \
    float u0 = hi2 ? t1 : s0;                           \
    float u2 = hi2 ? t3 : s2;                           \
    float v2 = __shfl_xor(u2, 8);                       \
    g = hi ? v2 : u0;                                   \
  }

// ===================== Layer-0, NB=4 compacted (128 WGs) =====================
// Chain-split: h-MFMAs run as two independent 2-deep chains (acc, acc2)
// merged with a vector add -> ~2 dependent-MFMA latencies off the step chain.
__global__ __launch_bounds__(512) void rec0c4(
    const float* __restrict__ x0,
    const float* __restrict__ WihF, const float* __restrict__ WhhF,
    const float* __restrict__ bF, const float* __restrict__ WihR,
    const float* __restrict__ WhhR, const float* __restrict__ bR,
    short* __restrict__ h1_out) {
  __shared__ short Hb[2][16][16][8];  // [buf][koct][col16][8]; cols 4-15 stay 0
  __shared__ short X2[2][8][16][8];   // K0=64; cols 4-15 stay 0

  const int tid = threadIdx.x, w = tid >> 6, lane = tid & 63;
  const int lg = lane >> 4, bcol = lane & 15;
  const int hi = (bcol >> 3) & 1, hi2 = (bcol >> 2) & 1;
  const int rr = bcol >> 2, ccol = bcol & 3;
  const int dir = blockIdx.x & 1, b0 = (blockIdx.x >> 1) * 4;
  const int j0 = w * 16 + lg * 4, jj = j0 + rr;
  const float* __restrict__ Wih = dir ? WihR : WihF;
  const float* __restrict__ Whh = dir ? WhhR : WhhF;
  const float* __restrict__ bias = dir ? bR : bF;
  auto tmap = [&](int s) { return dir ? (TT - 1 - s) : s; };

  short8 wx[4][2], wh[4][4];
  f32x4 bq[4];
#pragma unroll
  for (int q = 0; q < 4; ++q) {
    const float scale = (q == 2) ? (2.0f * L2E) : (-L2E);
    const int m = q * HH + w * 16 + bcol;
#pragma unroll
    for (int kk = 0; kk < 2; ++kk) {
      short8 f;
#pragma unroll
      for (int e = 0; e < 8; ++e) {
        const int k = kk * 32 + lg * 8 + e;
        float v = (k < DIN0) ? Wih[(size_t)m * DIN0 + k] : 0.0f;
        f[e] = f2b(v * scale);
      }
      wx[q][kk] = f;
    }
#pragma unroll
    for (int kk = 0; kk < 4; ++kk) {
      short8 f;
#pragma unroll
      for (int e = 0; e < 8; ++e)
        f[e] = f2b(Whh[(size_t)m * HH + kk * 32 + lg * 8 + e] * scale);
      wh[q][kk] = f;
    }
#pragma unroll
    for (int r = 0; r < 4; ++r) bq[q][r] = bias[q * HH + j0 + r] * scale;
  }

  for (int i = tid; i < (int)(sizeof(Hb) + sizeof(X2)) / 4; i += 512)
    ((int*)&Hb[0][0][0][0])[i] = 0;
  __syncthreads();

  // x staging: 40 threads cover 4 rows x 40 floats
  auto load_x = [&](int s) -> f32x4 {
    f32x4 v = {0.f, 0.f, 0.f, 0.f};
    if (tid < 40) {
      int ss = (s < TT) ? s : (TT - 1);
      v = *(const f32x4*)(x0 + ((size_t)(b0 + tid / 10) * TT + tmap(ss)) * DIN0 + (tid % 10) * 4);
    }
    return v;
  };
  auto stage_x = [&](int buf, const f32x4& v) {
    if (tid < 40) {
      short4v o;
      o[0] = f2b(v[0]); o[1] = f2b(v[1]); o[2] = f2b(v[2]); o[3] = f2b(v[3]);
      const int row = tid / 10, c4 = tid % 10;
      *(short4v*)&X2[buf][c4 >> 1][row][(c4 & 1) * 4] = o;
    }
  };
  auto prefill = [&](f32x4* acc, int p) {
#pragma unroll
    for (int kk = 0; kk < 2; ++kk) {
      const bf16x8 bx = as_bf(*(const short8*)&X2[p][kk * 4 + lg][bcol][0]);
#pragma unroll
      for (int q = 0; q < 4; ++q)
        acc[q] = __builtin_amdgcn_mfma_f32_16x16x32_bf16(
            as_bf(wx[q][kk]), bx, (kk == 0) ? bq[q] : acc[q], 0, 0, 0);
    }
  };

  stage_x(0, load_x(0));
  stage_x(1, load_x(1));
  f32x4 xst = load_x(2);
  __syncthreads();
  f32x4 accA[4], accB[4];
  prefill(accA, 0);
  bar_lgkm();

  float cst = 0.f;

  auto stepf = [&](int s, int cur, f32x4* acc, f32x4* accN) {
    f32x4 acc2[4];
#pragma unroll
    for (int q = 0; q < 4; ++q) acc2[q] = f32x4{0.f, 0.f, 0.f, 0.f};
#pragma unroll
    for (int kk = 0; kk < 2; ++kk) {
      const bf16x8 bh = as_bf(*(const short8*)&Hb[cur][kk * 4 + lg][bcol][0]);
      const bf16x8 bh2 = as_bf(*(const short8*)&Hb[cur][(kk + 2) * 4 + lg][bcol][0]);
#pragma unroll
      for (int q = 0; q < 4; ++q) {
        acc[q] = __builtin_amdgcn_mfma_f32_16x16x32_bf16(as_bf(wh[q][kk]), bh, acc[q], 0, 0, 0);
        acc2[q] = __builtin_amdgcn_mfma_f32_16x16x32_bf16(as_bf(wh[q][kk + 2]), bh2, acc2[q], 0, 0, 0);
      }
    }
#pragma unroll
    for (int q = 0; q < 4; ++q) acc[q] += acc2[q];
    float g0, g1, g2, g3;
    COMPACT4(g0, acc[0], hi2, hi);
    COMPACT4(g1, acc[1], hi2, hi);
    COMPACT4(g2, acc[2], hi2, hi);
    COMPACT4(g3, acc[3], hi2, hi);
    float hv;
    cell1L(g0, g1, g2, g3, cst, hv);
    short hs = f2b(hv);
    Hb[cur ^ 1][jj >> 3][ccol][jj & 7] = hs;
    h1_out[(((size_t)(b0 + ccol) * TT + tmap(s)) << 8) + dir * HH + jj] = hs;
    stage_x(cur, xst);
    xst = load_x(s + 3);
    prefill(accN, cur ^ 1);
    bar_lgkm();
  };
  for (int s = 0; s < TT; s += 2) {
    stepf(s, 0, accA, accB);
    stepf(s + 1, 1, accB, accA);
  }
}

// ===================== Layer-1 input projection (parallel, chunked; R8-proven) ====
// pre[((dir*16+bt16)*clen + sl)*8192 + w*1024 + q*256 + col*16 + lg*4 + r] (bf16)
__global__ __launch_bounds__(512, 1) void pre1(
    const short* __restrict__ h1, const float* __restrict__ WihF,
    const float* __restrict__ bF, const float* __restrict__ WihR,
    const float* __restrict__ bR, short* __restrict__ pre, int cs, int clen) {
  __shared__ short X[16 * 256];
  const int tid = threadIdx.x, w = tid >> 6, lane = tid & 63;
  const int lg = lane >> 4, bcol = lane & 15;
  const int gid = blockIdx.x;
  const int dir = gid & 1, bt16 = (gid >> 1) & 15, tc = gid >> 5;
  const float* __restrict__ Wih = dir ? WihR : WihF;
  const float* __restrict__ bias = dir ? bR : bF;
  const int b0 = bt16 * 16;

  short8 wx[4][8];
  f32x4 bq[4];
#pragma unroll
  for (int q = 0; q < 4; ++q) {
    const float scale = (q == 2) ? (2.0f * L2E) : (-L2E);
    const int m = q * HH + w * 16 + bcol;
#pragma unroll
    for (int kk = 0; kk < 8; ++kk) {
      short8 f;
#pragma unroll
      for (int e = 0; e < 8; ++e)
        f[e] = f2b(Wih[(size_t)m * 256 + kk * 32 + lg * 8 + e] * scale);
      wx[q][kk] = f;
    }
#pragma unroll
    for (int r = 0; r < 4; ++r) bq[q][r] = bias[q * HH + w * 16 + lg * 4 + r] * scale;
  }

  const int srow = tid >> 5, sch = tid & 31;
  for (int i = 0; i < 8; ++i) {
    const int sl = tc * 8 + i, sG = cs + sl;
    const int t = dir ? (TT - 1 - sG) : sG;
    short8 v = *(const short8*)(h1 + (((size_t)(b0 + srow) * TT + t) << 8) + sch * 8);
    *(short8*)((char*)X + srow * 512 + ((sch * 16) ^ ((srow & 7) << 4))) = v;
    __syncthreads();
    f32x4 acc[4] = {bq[0], bq[1], bq[2], bq[3]};
#pragma unroll
    for (int kk = 0; kk < 8; ++kk) {
      const bf16x8 bx = as_bf(*(const short8*)((const char*)X + bcol * 512 +
                                               ((kk * 64 + lg * 16) ^ ((bcol & 7) << 4))));
#pragma unroll
      for (int q = 0; q < 4; ++q)
        acc[q] = __builtin_amdgcn_mfma_f32_16x16x32_bf16(as_bf(wx[q][kk]), bx, acc[q], 0, 0, 0);
    }
    short* op = pre + ((((size_t)dir * 16 + bt16) * clen + sl) * 8 + w) * 1024 + bcol * 16 + lg * 4;
#pragma unroll
    for (int q = 0; q < 4; ++q) {
      short4v o;
      o[0] = f2b(acc[q][0]); o[1] = f2b(acc[q][1]);
      o[2] = f2b(acc[q][2]); o[3] = f2b(acc[q][3]);
      *(short4v*)(op + q * 256) = o;
    }
    __syncthreads();
  }
}

// ===================== Layer-1 recurrence, NB=4 compacted, chunked ==========
__global__ __launch_bounds__(512) void rec1c4(
    const short* __restrict__ pre, const float* __restrict__ WhhF,
    const float* __restrict__ WhhR, float* __restrict__ h2last,
    float* __restrict__ cstate, int* __restrict__ hstate, int cs, int clen) {
  __shared__ short Hb[2][16][16][8];
  const int tid = threadIdx.x, w = tid >> 6, lane = tid & 63;
  const int lg = lane >> 4, bcol = lane & 15;
  const int hi = (bcol >> 3) & 1, hi2 = (bcol >> 2) & 1;
  const int rr = bcol >> 2, ccol = bcol & 3;
  const int dir = blockIdx.x & 1, bt4 = blockIdx.x >> 1;
  const int b0 = bt4 * 4, bt16 = bt4 >> 2, colhi = (bt4 & 3) * 4;
  const int j0 = w * 16 + lg * 4, jj = j0 + rr;
  const int wg = blockIdx.x;
  const float* __restrict__ Whh = dir ? WhhR : WhhF;

  short8 wh[4][4];
#pragma unroll
  for (int q = 0; q < 4; ++q) {
    const float scale = (q == 2) ? (2.0f * L2E) : (-L2E);
    const int m = q * HH + w * 16 + bcol;
#pragma unroll
    for (int kk = 0; kk < 4; ++kk) {
      short8 f;
#pragma unroll
      for (int e = 0; e < 8; ++e)
        f[e] = f2b(Whh[(size_t)m * HH + kk * 32 + lg * 8 + e] * scale);
      wh[q][kk] = f;
    }
  }
  for (int i = tid; i < (int)sizeof(Hb) / 4; i += 512) ((int*)&Hb[0][0][0][0])[i] = 0;
  __syncthreads();

  float cst = 0.f;
  short hLast = 0;
  if (cs != 0) {
    cst = cstate[wg * 512 + tid];
    hLast = (short)hstate[wg * 512 + tid];
    Hb[0][jj >> 3][ccol][jj & 7] = hLast;
  }
  __syncthreads();

  // C-init: pre at (q, col = colhi + ccol, row j0+r).
  auto ldpre = [&](short4v* dst, int ls) {
    int l = (ls < clen) ? ls : (clen - 1);
    const short* bp = pre + ((((size_t)dir * 16 + bt16) * clen + l) * 8 + w) * 1024 +
                      (colhi + ccol) * 16 + lg * 4;
#pragma unroll
    for (int q = 0; q < 4; ++q) dst[q] = *(const short4v*)(bp + q * 256);
  };

  short4v pA[4], pB[4];
  ldpre(pA, 0);
  ldpre(pB, 1);

  auto stepf = [&](int ls, int cur, short4v* P) {
    f32x4 acc[4], acc2[4];
#pragma unroll
    for (int q = 0; q < 4; ++q) {
#pragma unroll
      for (int r = 0; r < 4; ++r) acc[q][r] = b2f(P[q][r]);
      acc2[q] = f32x4{0.f, 0.f, 0.f, 0.f};
    }
#pragma unroll
    for (int kk = 0; kk < 2; ++kk) {
      const bf16x8 bh = as_bf(*(const short8*)&Hb[cur][kk * 4 + lg][bcol][0]);
      const bf16x8 bh2 = as_bf(*(const short8*)&Hb[cur][(kk + 2) * 4 + lg][bcol][0]);
#pragma unroll
      for (int q = 0; q < 4; ++q) {
        acc[q] = __builtin_amdgcn_mfma_f32_16x16x32_bf16(as_bf(wh[q][kk]), bh, acc[q], 0, 0, 0);
        acc2[q] = __builtin_amdgcn_mfma_f32_16x16x32_bf16(as_bf(wh[q][kk + 2]), bh2, acc2[q], 0, 0, 0);
      }
    }
#pragma unroll
    for (int q = 0; q < 4; ++q) acc[q] += acc2[q];
    float g0, g1, g2, g3;
    COMPACT4(g0, acc[0], hi2, hi);
    COMPACT4(g1, acc[1], hi2, hi);
    COMPACT4(g2, acc[2], hi2, hi);
    COMPACT4(g3, acc[3], hi2, hi);
    float hv;
    cell1L(g0, g1, g2, g3, cst, hv);
    short hs = f2b(hv);
    hLast = hs;
    Hb[cur ^ 1][jj >> 3][ccol][jj & 7] = hs;
    const int sG = cs + ls;
    if (sG == (dir ? 0 : TT - 1))
      h2last[((size_t)(b0 + ccol) << 8) + dir * HH + jj] = hv;
    ldpre(P, ls + 2);
    bar_lgkm();
  };
  for (int ls = 0; ls < clen; ls += 2) {
    stepf(ls, 0, pA);
    stepf(ls + 1, 1, pB);
  }
  cstate[wg * 512 + tid] = cst;
  hstate[wg * 512 + tid] = (int)hLast;
}

// ===================== Layer-1 fused fallback (R8-proven) ============
__global__ __launch_bounds__(512) void rec1_fused(
    const short* __restrict__ h1, const float* __restrict__ Wih_f,
    const float* __restrict__ Whh_f, const float* __restrict__ b_f,
    const float* __restrict__ Wih_r, const float* __restrict__ Whh_r,
    const float* __restrict__ b_r, float* __restrict__ h2last) {
  __shared__ short Hb[2][16][16][8];
  __shared__ char Xraw[16384];
  const int tid = threadIdx.x, w = tid >> 6, lane = tid & 63;
  const int lg = lane >> 4, bcol = lane & 15;
  const int dir = blockIdx.x & 1, b0 = (blockIdx.x >> 1) * 16;
  const int j0 = w * 16 + lg * 4;
  const float* __restrict__ Wih = dir ? Wih_r : Wih_f;
  const float* __restrict__ Whh = dir ? Whh_r : Whh_f;
  const float* __restrict__ bias = dir ? b_r : b_f;
  auto tmap = [&](int s) { return dir ? (TT - 1 - s) : s; };

  short8 wx[4][8], wh[4][4];
  f32x4 bq[4];
#pragma unroll
  for (int q = 0; q < 4; ++q) {
    const float scale = (q == 2) ? (2.0f * L2E) : (-L2E);
    const int m = q * HH + w * 16 + bcol;
#pragma unroll
    for (int kk = 0; kk < 8; ++kk) {
      short8 f;
#pragma unroll
      for (int e = 0; e < 8; ++e)
        f[e] = f2b(Wih[(size_t)m * 256 + kk * 32 + lg * 8 + e] * scale);
      wx[q][kk] = f;
    }
#pragma unroll
    for (int kk = 0; kk < 4; ++kk) {
      short8 f;
#pragma unroll
      for (int e = 0; e < 8; ++e)
        f[e] = f2b(Whh[(size_t)m * HH + kk * 32 + lg * 8 + e] * scale);
      wh[q][kk] = f;
    }
#pragma unroll
    for (int r = 0; r < 4; ++r) bq[q][r] = bias[q * HH + j0 + r] * scale;
  }
  for (int i = tid; i < 2 * 16 * 16 * 4; i += 512) ((int*)Hb)[i] = 0;
  __syncthreads();

  const int xr1 = tid >> 5;
  const int xcb = ((tid << 4) ^ (((tid >> 5) & 7) << 4)) & 511;
  auto ldx = [&](int p, int kk) -> short8 {
    int byte = ((bcol << 9) + (kk << 6) + (lg << 4)) ^ ((bcol & 7) << 4);
    return *(const short8*)(Xraw + p * 8192 + byte);
  };
  auto ldg = [&](int s) -> short8 {
    int ss = (s < TT) ? s : (TT - 1);
    return *(const short8*)((const char*)h1 + (((size_t)(b0 + xr1) * TT + tmap(ss)) << 9) + xcb);
  };
  {
    short8 v0 = ldg(0), v1 = ldg(1);
    *(short8*)(Xraw + tid * 16) = v0;
    *(short8*)(Xraw + 8192 + tid * 16) = v1;
  }
  short8 xstage = ldg(2);
  __syncthreads();

  f32x4 acc[4] = {bq[0], bq[1], bq[2], bq[3]};
#pragma unroll
  for (int kk = 0; kk < 8; ++kk) {
    bf16x8 bx = as_bf(ldx(0, kk));
#pragma unroll
    for (int q = 0; q < 4; ++q)
      acc[q] = __builtin_amdgcn_mfma_f32_16x16x32_bf16(as_bf(wx[q][kk]), bx, acc[q], 0, 0, 0);
  }
  bar_lgkm();

  f32x4 cst = {0.f, 0.f, 0.f, 0.f};
  auto stepf = [&](int s, int buf) {
    *(short8*)(Xraw + buf * 8192 + tid * 16) = xstage;
    xstage = ldg(s + 3);
#pragma unroll
    for (int kk = 0; kk < 4; ++kk) {
      bf16x8 bh = as_bf(*(const short8*)&Hb[buf][kk * 4 + lg][bcol][0]);
#pragma unroll
      for (int q = 0; q < 4; ++q)
        acc[q] = __builtin_amdgcn_mfma_f32_16x16x32_bf16(as_bf(wh[q][kk]), bh, acc[q], 0, 0, 0);
    }
    float hv0, hv1, hv2, hv3;
    {
      float c0 = cst[0], c1 = cst[1];
      cell2(acc[0][0], acc[1][0], acc[2][0], acc[3][0],
            acc[0][1], acc[1][1], acc[2][1], acc[3][1], c0, c1, hv0, hv1);
      cst[0] = c0; cst[1] = c1;
      float c2 = cst[2], c3 = cst[3];
      cell2(acc[0][2], acc[1][2], acc[2][2], acc[3][2],
            acc[0][3], acc[1][3], acc[2][3], acc[3][3], c2, c3, hv2, hv3);
      cst[2] = c2; cst[3] = c3;
    }
    short4v hp;
    hp[0] = f2b(hv0); hp[1] = f2b(hv1); hp[2] = f2b(hv2); hp[3] = f2b(hv3);
    *(short4v*)&Hb[buf ^ 1][j0 >> 3][bcol][j0 & 7] = hp;
    if ((dir == 0 && s == TT - 1) || (dir == 1 && s == 0)) {
      f32x4 hf;
      hf[0] = hv0; hf[1] = hv1; hf[2] = hv2; hf[3] = hv3;
      *(f32x4*)(h2last + ((size_t)(b0 + bcol) << 8) + dir * HH + j0) = hf;
    }
#pragma unroll
    for (int q = 0; q < 4; ++q) acc[q] = bq[q];
#pragma unroll
    for (int kk = 0; kk < 8; ++kk) {
      bf16x8 bx = as_bf(ldx(buf ^ 1, kk));
#pragma unroll
      for (int q = 0; q < 4; ++q)
        acc[q] = __builtin_amdgcn_mfma_f32_16x16x32_bf16(as_bf(wx[q][kk]), bx, acc[q], 0, 0, 0);
    }
    bar_lgkm();
  };
  for (int s = 0; s < TT; s += 2) {
    stepf(s, 0);
    stepf(s + 1, 1);
  }
}

__global__ void fc_kernel(const float* __restrict__ h2last,
                          const float* __restrict__ fcw,
                          const float* __restrict__ fcb,
                          float* __restrict__ out) {
  const int gid = blockIdx.x * blockDim.x + threadIdx.x;
  if (gid >= BB * NCLS) return;
  const int b = gid / NCLS, n = gid % NCLS;
  const float* hp = h2last + (size_t)b * 256;
  const float* wp = fcw + (size_t)n * 256;
  float s = fcb[n];
#pragma unroll 8
  for (int j = 0; j < 256; ++j) s = fmaf(hp[j], wp[j], s);
  out[gid] = s;
}

extern "C" void kernel_launch(void* const* d_in, const int* in_sizes, int n_in,
                              void* d_out, int out_size, void* d_ws, size_t ws_size,
                              hipStream_t stream) {
  const float* x     = (const float*)d_in[0];
  const float* Wih0f = (const float*)d_in[1];
  const float* Whh0f = (const float*)d_in[2];
  const float* b0f   = (const float*)d_in[3];
  const float* Wih0r = (const float*)d_in[4];
  const float* Whh0r = (const float*)d_in[5];
  const float* b0r   = (const float*)d_in[6];
  const float* Wih1f = (const float*)d_in[7];
  const float* Whh1f = (const float*)d_in[8];
  const float* b1f   = (const float*)d_in[9];
  const float* Wih1r = (const float*)d_in[10];
  const float* Whh1r = (const float*)d_in[11];
  const float* b1r   = (const float*)d_in[12];
  const float* fcw   = (const float*)d_in[13];
  const float* fcb   = (const float*)d_in[14];

  short* h1 = (short*)d_ws;                                        // 64MB
  float* h2last = (float*)((char*)d_ws + (64ull << 20));           // 256KB
  float* cstate = (float*)((char*)d_ws + (64ull << 20) + (512ull << 10));  // 256KB
  int* hstate = (int*)((char*)d_ws + (64ull << 20) + (768ull << 10));      // 256KB
  short* pre = (short*)((char*)d_ws + (66ull << 20));

  // chunk: per-t pre bytes = 2*16*8*1024*2 = 512KB
  size_t budget = ws_size > (66ull << 20) ? ws_size - (66ull << 20) : 0;
  int chunkT = 0;
  const int cands[7] = {512, 256, 128, 64, 32, 16, 8};
  for (int i = 0; i < 7; ++i)
    if ((size_t)cands[i] * (512ull << 10) <= budget) { chunkT = cands[i]; break; }

  rec0c4<<<dim3(128), dim3(512), 0, stream>>>(
      x, Wih0f, Whh0f, b0f, Wih0r, Whh0r, b0r, h1);

  if (chunkT > 0) {
    for (int cs = 0; cs < TT; cs += chunkT) {
      pre1<<<dim3(4 * chunkT), dim3(512), 0, stream>>>(
          h1, Wih1f, b1f, Wih1r, b1r, pre, cs, chunkT);
      rec1c4<<<dim3(128), dim3(512), 0, stream>>>(
          pre, Whh1f, Whh1r, h2last, cstate, hstate, cs, chunkT);
    }
  } else {
    rec1_fused<<<dim3(32), dim3(512), 0, stream>>>(
        h1, Wih1f, Whh1f, b1f, Wih1r, Whh1r, b1r, h2last);
  }

  fc_kernel<<<dim3((BB * NCLS + 255) / 256), dim3(256), 0, stream>>>(
      h2last, fcw, fcb, (float*)d_out);
}

// Round 15
// 989.972 us; speedup vs baseline: 1.0258x; 1.0258x over previous
//
#include <hip/hip_runtime.h>
#include <hip/hip_bf16.h>

typedef short short8 __attribute__((ext_vector_type(8)));
typedef short short4v __attribute__((ext_vector_type(4)));
typedef float f32x4 __attribute__((ext_vector_type(4)));
typedef __bf16 bf16x8 __attribute__((ext_vector_type(8)));

#define DEVI static __device__ __forceinline__

#if __has_builtin(__builtin_amdgcn_exp2f)
#define EXP2(x) __builtin_amdgcn_exp2f(x)
#else
#define EXP2(x) exp2f(x)
#endif
#if __has_builtin(__builtin_amdgcn_rcpf)
#define RCP(x) __builtin_amdgcn_rcpf(x)
#else
#define RCP(x) (1.0f / (x))
#endif

static constexpr int BB = 256, TT = 512, DIN0 = 40, HH = 128, NCLS = 7;
static constexpr float L2E = 1.44269504088896f;

DEVI short f2b(float x) {
  union { __hip_bfloat16 h; short s; } u;
  u.h = __float2bfloat16(x);
  return u.s;
}
DEVI float b2f(short s) {
  union { unsigned u; float f; } v;
  v.u = ((unsigned)(unsigned short)s) << 16;
  return v.f;
}
DEVI bf16x8 as_bf(short8 s) { return __builtin_bit_cast(bf16x8, s); }

DEVI void bar_lgkm() {
  asm volatile("s_waitcnt lgkmcnt(0)\n\ts_barrier" ::: "memory");
}

// 1-cell LSTM update: 5 exp2 + 2 rcp (Montgomery-4). Gates pre-scaled:
// i,f,o by -log2e; g by 2*log2e. Clamp 14 -> 4-product <= 2^56 finite;
// saturation err <= 6.1e-5 (threshold 2.4e-3).
DEVI void cell1(float gi, float gf, float gg, float go, float& c, float& h) {
  float d0 = 1.f + EXP2(fminf(gi, 14.f));
  float d1 = 1.f + EXP2(fminf(gf, 14.f));
  float d2 = 1.f + EXP2(fminf(gg, 14.f));
  float d3 = 1.f + EXP2(fminf(go, 14.f));
  float p1 = d0 * d1, p2 = p1 * d2, p3 = p2 * d3;
  float R = RCP(p3);
  float r3 = R * p2; R *= d3;
  float r2 = R * p1; R *= d2;
  float r1 = R * d0, r0 = R * d1;
  float tg = 1.f - 2.f * r2;
  c = r1 * c + r0 * tg;
  float q0 = 1.f + EXP2(fminf(c * (2.f * L2E), 30.f));
  h = r3 * (1.f - 2.f * RCP(q0));
}

// 2-cell variant for the fused fallback (R8-proven).
DEVI void cell2(float gi0, float gf0, float gg0, float go0,
                float gi1, float gf1, float gg1, float go1,
                float& c0, float& c1, float& h0, float& h1) {
  float d0 = 1.f + EXP2(fminf(gi0, 14.f));
  float d1 = 1.f + EXP2(fminf(gf0, 14.f));
  float d2 = 1.f + EXP2(fminf(gg0, 14.f));
  float d3 = 1.f + EXP2(fminf(go0, 14.f));
  float d4 = 1.f + EXP2(fminf(gi1, 14.f));
  float d5 = 1.f + EXP2(fminf(gf1, 14.f));
  float d6 = 1.f + EXP2(fminf(gg1, 14.f));
  float d7 = 1.f + EXP2(fminf(go1, 14.f));
  float p1 = d0 * d1, p2 = p1 * d2, p3 = p2 * d3, p4 = p3 * d4;
  float p5 = p4 * d5, p6 = p5 * d6, p7 = p6 * d7;
  float R = RCP(p7);
  float r7 = R * p6; R *= d7;
  float r6 = R * p5; R *= d6;
  float r5 = R * p4; R *= d5;
  float r4 = R * p3; R *= d4;
  float r3 = R * p2; R *= d3;
  float r2 = R * p1; R *= d2;
  float r1 = R * d0, r0 = R * d1;
  float tg0 = 1.f - 2.f * r2, tg1 = 1.f - 2.f * r6;
  c0 = r1 * c0 + r0 * tg0;
  c1 = r5 * c1 + r4 * tg1;
  float q0 = 1.f + EXP2(fminf(c0 * (2.f * L2E), 30.f));
  float q1 = 1.f + EXP2(fminf(c1 * (2.f * L2E), 30.f));
  float Rq = RCP(q0 * q1);
  h0 = r3 * (1.f - 2.f * Rq * q1);
  h1 = r7 * (1.f - 2.f * Rq * q0);
}

// Two-stage compaction: move cell (col=c, r) to lane c + 4r (within 16-lane
// group). Only acc values from lanes bcol<4 are consumed.
#define COMPACT4(g, acc, hi2, hi)                       \
  {                                                     \
    float s0 = acc[0], s1 = acc[1], s2 = acc[2], s3 = acc[3]; \
    float t1 = __shfl_xor(s1, 4);                       \
    float t3 = __shfl_xor(s3, 4);                       \
    float u0 = hi2 ? t1 : s0;                           \
    float u2 = hi2 ? t3 : s2;                           \
    float v2 = __shfl_xor(u2, 8);                       \
    g = hi ? v2 : u0;                                   \
  }

// ===================== Layer-0, NB=4 compacted (128 WGs) =====================
__global__ __launch_bounds__(512) void rec0c4(
    const float* __restrict__ x0,
    const float* __restrict__ WihF, const float* __restrict__ WhhF,
    const float* __restrict__ bF, const float* __restrict__ WihR,
    const float* __restrict__ WhhR, const float* __restrict__ bR,
    short* __restrict__ h1_out) {
  __shared__ short Hb[2][16][16][8];  // [buf][koct][col16][8]; cols 4-15 stay 0
  __shared__ short X2[2][8][16][8];   // K0=64; cols 4-15 stay 0

  const int tid = threadIdx.x, w = tid >> 6, lane = tid & 63;
  const int lg = lane >> 4, bcol = lane & 15;
  const int hi = (bcol >> 3) & 1, hi2 = (bcol >> 2) & 1;
  const int rr = bcol >> 2, ccol = bcol & 3;
  const int dir = blockIdx.x & 1, b0 = (blockIdx.x >> 1) * 4;
  const int j0 = w * 16 + lg * 4, jj = j0 + rr;
  const float* __restrict__ Wih = dir ? WihR : WihF;
  const float* __restrict__ Whh = dir ? WhhR : WhhF;
  const float* __restrict__ bias = dir ? bR : bF;
  auto tmap = [&](int s) { return dir ? (TT - 1 - s) : s; };

  short8 wx[4][2], wh[4][4];
  f32x4 bq[4];
#pragma unroll
  for (int q = 0; q < 4; ++q) {
    const float scale = (q == 2) ? (2.0f * L2E) : (-L2E);
    const int m = q * HH + w * 16 + bcol;
#pragma unroll
    for (int kk = 0; kk < 2; ++kk) {
      short8 f;
#pragma unroll
      for (int e = 0; e < 8; ++e) {
        const int k = kk * 32 + lg * 8 + e;
        float v = (k < DIN0) ? Wih[(size_t)m * DIN0 + k] : 0.0f;
        f[e] = f2b(v * scale);
      }
      wx[q][kk] = f;
    }
#pragma unroll
    for (int kk = 0; kk < 4; ++kk) {
      short8 f;
#pragma unroll
      for (int e = 0; e < 8; ++e)
        f[e] = f2b(Whh[(size_t)m * HH + kk * 32 + lg * 8 + e] * scale);
      wh[q][kk] = f;
    }
#pragma unroll
    for (int r = 0; r < 4; ++r) bq[q][r] = bias[q * HH + j0 + r] * scale;
  }

  for (int i = tid; i < (int)(sizeof(Hb) + sizeof(X2)) / 4; i += 512)
    ((int*)&Hb[0][0][0][0])[i] = 0;
  __syncthreads();

  // x staging: 40 threads cover 4 rows x 40 floats
  auto load_x = [&](int s) -> f32x4 {
    f32x4 v = {0.f, 0.f, 0.f, 0.f};
    if (tid < 40) {
      int ss = (s < TT) ? s : (TT - 1);
      v = *(const f32x4*)(x0 + ((size_t)(b0 + tid / 10) * TT + tmap(ss)) * DIN0 + (tid % 10) * 4);
    }
    return v;
  };
  auto stage_x = [&](int buf, const f32x4& v) {
    if (tid < 40) {
      short4v o;
      o[0] = f2b(v[0]); o[1] = f2b(v[1]); o[2] = f2b(v[2]); o[3] = f2b(v[3]);
      const int row = tid / 10, c4 = tid % 10;
      *(short4v*)&X2[buf][c4 >> 1][row][(c4 & 1) * 4] = o;
    }
  };
  auto prefill = [&](f32x4* acc, int p) {
#pragma unroll
    for (int kk = 0; kk < 2; ++kk) {
      const bf16x8 bx = as_bf(*(const short8*)&X2[p][kk * 4 + lg][bcol][0]);
#pragma unroll
      for (int q = 0; q < 4; ++q)
        acc[q] = __builtin_amdgcn_mfma_f32_16x16x32_bf16(
            as_bf(wx[q][kk]), bx, (kk == 0) ? bq[q] : acc[q], 0, 0, 0);
    }
  };

  stage_x(0, load_x(0));
  stage_x(1, load_x(1));
  f32x4 xst = load_x(2);
  __syncthreads();
  f32x4 accA[4], accB[4];
  prefill(accA, 0);
  bar_lgkm();

  float cst = 0.f;

  auto stepf = [&](int s, int cur, f32x4* acc, f32x4* accN) {
#pragma unroll
    for (int kk = 0; kk < 4; ++kk) {
      const bf16x8 bh = as_bf(*(const short8*)&Hb[cur][kk * 4 + lg][bcol][0]);
#pragma unroll
      for (int q = 0; q < 4; ++q)
        acc[q] = __builtin_amdgcn_mfma_f32_16x16x32_bf16(as_bf(wh[q][kk]), bh, acc[q], 0, 0, 0);
    }
    float g0, g1, g2, g3;
    COMPACT4(g0, acc[0], hi2, hi);
    COMPACT4(g1, acc[1], hi2, hi);
    COMPACT4(g2, acc[2], hi2, hi);
    COMPACT4(g3, acc[3], hi2, hi);
    float hv;
    cell1(g0, g1, g2, g3, cst, hv);
    short hs = f2b(hv);
    Hb[cur ^ 1][jj >> 3][ccol][jj & 7] = hs;
    h1_out[(((size_t)(b0 + ccol) * TT + tmap(s)) << 8) + dir * HH + jj] = hs;
    stage_x(cur, xst);
    xst = load_x(s + 3);
    prefill(accN, cur ^ 1);
    bar_lgkm();
  };
  for (int s = 0; s < TT; s += 2) {
    stepf(s, 0, accA, accB);
    stepf(s + 1, 1, accB, accA);
  }
}

// ===================== Layer-1 input projection (parallel, chunked; R8-proven) ====
// pre[((dir*16+bt16)*clen + sl)*8192 + w*1024 + q*256 + col*16 + lg*4 + r] (bf16)
__global__ __launch_bounds__(512, 1) void pre1(
    const short* __restrict__ h1, const float* __restrict__ WihF,
    const float* __restrict__ bF, const float* __restrict__ WihR,
    const float* __restrict__ bR, short* __restrict__ pre, int cs, int clen) {
  __shared__ short X[16 * 256];
  const int tid = threadIdx.x, w = tid >> 6, lane = tid & 63;
  const int lg = lane >> 4, bcol = lane & 15;
  const int gid = blockIdx.x;
  const int dir = gid & 1, bt16 = (gid >> 1) & 15, tc = gid >> 5;
  const float* __restrict__ Wih = dir ? WihR : WihF;
  const float* __restrict__ bias = dir ? bR : bF;
  const int b0 = bt16 * 16;

  short8 wx[4][8];
  f32x4 bq[4];
#pragma unroll
  for (int q = 0; q < 4; ++q) {
    const float scale = (q == 2) ? (2.0f * L2E) : (-L2E);
    const int m = q * HH + w * 16 + bcol;
#pragma unroll
    for (int kk = 0; kk < 8; ++kk) {
      short8 f;
#pragma unroll
      for (int e = 0; e < 8; ++e)
        f[e] = f2b(Wih[(size_t)m * 256 + kk * 32 + lg * 8 + e] * scale);
      wx[q][kk] = f;
    }
#pragma unroll
    for (int r = 0; r < 4; ++r) bq[q][r] = bias[q * HH + w * 16 + lg * 4 + r] * scale;
  }

  const int srow = tid >> 5, sch = tid & 31;
  for (int i = 0; i < 8; ++i) {
    const int sl = tc * 8 + i, sG = cs + sl;
    const int t = dir ? (TT - 1 - sG) : sG;
    short8 v = *(const short8*)(h1 + (((size_t)(b0 + srow) * TT + t) << 8) + sch * 8);
    *(short8*)((char*)X + srow * 512 + ((sch * 16) ^ ((srow & 7) << 4))) = v;
    __syncthreads();
    f32x4 acc[4] = {bq[0], bq[1], bq[2], bq[3]};
#pragma unroll
    for (int kk = 0; kk < 8; ++kk) {
      const bf16x8 bx = as_bf(*(const short8*)((const char*)X + bcol * 512 +
                                               ((kk * 64 + lg * 16) ^ ((bcol & 7) << 4))));
#pragma unroll
      for (int q = 0; q < 4; ++q)
        acc[q] = __builtin_amdgcn_mfma_f32_16x16x32_bf16(as_bf(wx[q][kk]), bx, acc[q], 0, 0, 0);
    }
    short* op = pre + ((((size_t)dir * 16 + bt16) * clen + sl) * 8 + w) * 1024 + bcol * 16 + lg * 4;
#pragma unroll
    for (int q = 0; q < 4; ++q) {
      short4v o;
      o[0] = f2b(acc[q][0]); o[1] = f2b(acc[q][1]);
      o[2] = f2b(acc[q][2]); o[3] = f2b(acc[q][3]);
      *(short4v*)(op + q * 256) = o;
    }
    __syncthreads();
  }
}

// ===================== Layer-1 recurrence, NB=4 compacted, chunked ==========
__global__ __launch_bounds__(512) void rec1c4(
    const short* __restrict__ pre, const float* __restrict__ WhhF,
    const float* __restrict__ WhhR, float* __restrict__ h2last,
    float* __restrict__ cstate, int* __restrict__ hstate, int cs, int clen) {
  __shared__ short Hb[2][16][16][8];
  const int tid = threadIdx.x, w = tid >> 6, lane = tid & 63;
  const int lg = lane >> 4, bcol = lane & 15;
  const int hi = (bcol >> 3) & 1, hi2 = (bcol >> 2) & 1;
  const int rr = bcol >> 2, ccol = bcol & 3;
  const int dir = blockIdx.x & 1, bt4 = blockIdx.x >> 1;
  const int b0 = bt4 * 4, bt16 = bt4 >> 2, colhi = (bt4 & 3) * 4;
  const int j0 = w * 16 + lg * 4, jj = j0 + rr;
  const int wg = blockIdx.x;
  const float* __restrict__ Whh = dir ? WhhR : WhhF;

  short8 wh[4][4];
#pragma unroll
  for (int q = 0; q < 4; ++q) {
    const float scale = (q == 2) ? (2.0f * L2E) : (-L2E);
    const int m = q * HH + w * 16 + bcol;
#pragma unroll
    for (int kk = 0; kk < 4; ++kk) {
      short8 f;
#pragma unroll
      for (int e = 0; e < 8; ++e)
        f[e] = f2b(Whh[(size_t)m * HH + kk * 32 + lg * 8 + e] * scale);
      wh[q][kk] = f;
    }
  }
  for (int i = tid; i < (int)sizeof(Hb) / 4; i += 512) ((int*)&Hb[0][0][0][0])[i] = 0;
  __syncthreads();

  float cst = 0.f;
  short hLast = 0;
  if (cs != 0) {
    cst = cstate[wg * 512 + tid];
    hLast = (short)hstate[wg * 512 + tid];
    Hb[0][jj >> 3][ccol][jj & 7] = hLast;
  }
  __syncthreads();

  // C-init: pre at (q, col = colhi + ccol, row j0+r).
  auto ldpre = [&](short4v* dst, int ls) {
    int l = (ls < clen) ? ls : (clen - 1);
    const short* bp = pre + ((((size_t)dir * 16 + bt16) * clen + l) * 8 + w) * 1024 +
                      (colhi + ccol) * 16 + lg * 4;
#pragma unroll
    for (int q = 0; q < 4; ++q) dst[q] = *(const short4v*)(bp + q * 256);
  };

  short4v pA[4], pB[4];
  ldpre(pA, 0);
  ldpre(pB, 1);

  auto stepf = [&](int ls, int cur, short4v* P) {
    f32x4 acc[4];
#pragma unroll
    for (int q = 0; q < 4; ++q)
#pragma unroll
      for (int r = 0; r < 4; ++r) acc[q][r] = b2f(P[q][r]);
#pragma unroll
    for (int kk = 0; kk < 4; ++kk) {
      const bf16x8 bh = as_bf(*(const short8*)&Hb[cur][kk * 4 + lg][bcol][0]);
#pragma unroll
      for (int q = 0; q < 4; ++q)
        acc[q] = __builtin_amdgcn_mfma_f32_16x16x32_bf16(as_bf(wh[q][kk]), bh, acc[q], 0, 0, 0);
    }
    float g0, g1, g2, g3;
    COMPACT4(g0, acc[0], hi2, hi);
    COMPACT4(g1, acc[1], hi2, hi);
    COMPACT4(g2, acc[2], hi2, hi);
    COMPACT4(g3, acc[3], hi2, hi);
    float hv;
    cell1(g0, g1, g2, g3, cst, hv);
    short hs = f2b(hv);
    hLast = hs;
    Hb[cur ^ 1][jj >> 3][ccol][jj & 7] = hs;
    const int sG = cs + ls;
    if (sG == (dir ? 0 : TT - 1))
      h2last[((size_t)(b0 + ccol) << 8) + dir * HH + jj] = hv;
    ldpre(P, ls + 2);
    bar_lgkm();
  };
  for (int ls = 0; ls < clen; ls += 2) {
    stepf(ls, 0, pA);
    stepf(ls + 1, 1, pB);
  }
  cstate[wg * 512 + tid] = cst;
  hstate[wg * 512 + tid] = (int)hLast;
}

// ===================== Layer-1 fused fallback (R8-proven) ============
__global__ __launch_bounds__(512) void rec1_fused(
    const short* __restrict__ h1, const float* __restrict__ Wih_f,
    const float* __restrict__ Whh_f, const float* __restrict__ b_f,
    const float* __restrict__ Wih_r, const float* __restrict__ Whh_r,
    const float* __restrict__ b_r, float* __restrict__ h2last) {
  __shared__ short Hb[2][16][16][8];
  __shared__ char Xraw[16384];
  const int tid = threadIdx.x, w = tid >> 6, lane = tid & 63;
  const int lg = lane >> 4, bcol = lane & 15;
  const int dir = blockIdx.x & 1, b0 = (blockIdx.x >> 1) * 16;
  const int j0 = w * 16 + lg * 4;
  const float* __restrict__ Wih = dir ? Wih_r : Wih_f;
  const float* __restrict__ Whh = dir ? Whh_r : Whh_f;
  const float* __restrict__ bias = dir ? b_r : b_f;
  auto tmap = [&](int s) { return dir ? (TT - 1 - s) : s; };

  short8 wx[4][8], wh[4][4];
  f32x4 bq[4];
#pragma unroll
  for (int q = 0; q < 4; ++q) {
    const float scale = (q == 2) ? (2.0f * L2E) : (-L2E);
    const int m = q * HH + w * 16 + bcol;
#pragma unroll
    for (int kk = 0; kk < 8; ++kk) {
      short8 f;
#pragma unroll
      for (int e = 0; e < 8; ++e)
        f[e] = f2b(Wih[(size_t)m * 256 + kk * 32 + lg * 8 + e] * scale);
      wx[q][kk] = f;
    }
#pragma unroll
    for (int kk = 0; kk < 4; ++kk) {
      short8 f;
#pragma unroll
      for (int e = 0; e < 8; ++e)
        f[e] = f2b(Whh[(size_t)m * HH + kk * 32 + lg * 8 + e] * scale);
      wh[q][kk] = f;
    }
#pragma unroll
    for (int r = 0; r < 4; ++r) bq[q][r] = bias[q * HH + j0 + r] * scale;
  }
  for (int i = tid; i < 2 * 16 * 16 * 4; i += 512) ((int*)Hb)[i] = 0;
  __syncthreads();

  const int xr1 = tid >> 5;
  const int xcb = ((tid << 4) ^ (((tid >> 5) & 7) << 4)) & 511;
  auto ldx = [&](int p, int kk) -> short8 {
    int byte = ((bcol << 9) + (kk << 6) + (lg << 4)) ^ ((bcol & 7) << 4);
    return *(const short8*)(Xraw + p * 8192 + byte);
  };
  auto ldg = [&](int s) -> short8 {
    int ss = (s < TT) ? s : (TT - 1);
    return *(const short8*)((const char*)h1 + (((size_t)(b0 + xr1) * TT + tmap(ss)) << 9) + xcb);
  };
  {
    short8 v0 = ldg(0), v1 = ldg(1);
    *(short8*)(Xraw + tid * 16) = v0;
    *(short8*)(Xraw + 8192 + tid * 16) = v1;
  }
  short8 xstage = ldg(2);
  __syncthreads();

  f32x4 acc[4] = {bq[0], bq[1], bq[2], bq[3]};
#pragma unroll
  for (int kk = 0; kk < 8; ++kk) {
    bf16x8 bx = as_bf(ldx(0, kk));
#pragma unroll
    for (int q = 0; q < 4; ++q)
      acc[q] = __builtin_amdgcn_mfma_f32_16x16x32_bf16(as_bf(wx[q][kk]), bx, acc[q], 0, 0, 0);
  }
  bar_lgkm();

  f32x4 cst = {0.f, 0.f, 0.f, 0.f};
  auto stepf = [&](int s, int buf) {
    *(short8*)(Xraw + buf * 8192 + tid * 16) = xstage;
    xstage = ldg(s + 3);
#pragma unroll
    for (int kk = 0; kk < 4; ++kk) {
      bf16x8 bh = as_bf(*(const short8*)&Hb[buf][kk * 4 + lg][bcol][0]);
#pragma unroll
      for (int q = 0; q < 4; ++q)
        acc[q] = __builtin_amdgcn_mfma_f32_16x16x32_bf16(as_bf(wh[q][kk]), bh, acc[q], 0, 0, 0);
    }
    float hv0, hv1, hv2, hv3;
    {
      float c0 = cst[0], c1 = cst[1];
      cell2(acc[0][0], acc[1][0], acc[2][0], acc[3][0],
            acc[0][1], acc[1][1], acc[2][1], acc[3][1], c0, c1, hv0, hv1);
      cst[0] = c0; cst[1] = c1;
      float c2 = cst[2], c3 = cst[3];
      cell2(acc[0][2], acc[1][2], acc[2][2], acc[3][2],
            acc[0][3], acc[1][3], acc[2][3], acc[3][3], c2, c3, hv2, hv3);
      cst[2] = c2; cst[3] = c3;
    }
    short4v hp;
    hp[0] = f2b(hv0); hp[1] = f2b(hv1); hp[2] = f2b(hv2); hp[3] = f2b(hv3);
    *(short4v*)&Hb[buf ^ 1][j0 >> 3][bcol][j0 & 7] = hp;
    if ((dir == 0 && s == TT - 1) || (dir == 1 && s == 0)) {
      f32x4 hf;
      hf[0] = hv0; hf[1] = hv1; hf[2] = hv2; hf[3] = hv3;
      *(f32x4*)(h2last + ((size_t)(b0 + bcol) << 8) + dir * HH + j0) = hf;
    }
#pragma unroll
    for (int q = 0; q < 4; ++q) acc[q] = bq[q];
#pragma unroll
    for (int kk = 0; kk < 8; ++kk) {
      bf16x8 bx = as_bf(ldx(buf ^ 1, kk));
#pragma unroll
      for (int q = 0; q < 4; ++q)
        acc[q] = __builtin_amdgcn_mfma_f32_16x16x32_bf16(as_bf(wx[q][kk]), bx, acc[q], 0, 0, 0);
    }
    bar_lgkm();
  };
  for (int s = 0; s < TT; s += 2) {
    stepf(s, 0);
    stepf(s + 1, 1);
  }
}

__global__ void fc_kernel(const float* __restrict__ h2last,
                          const float* __restrict__ fcw,
                          const float* __restrict__ fcb,
                          float* __restrict__ out) {
  const int gid = blockIdx.x * blockDim.x + threadIdx.x;
  if (gid >= BB * NCLS) return;
  const int b = gid / NCLS, n = gid % NCLS;
  const float* hp = h2last + (size_t)b * 256;
  const float* wp = fcw + (size_t)n * 256;
  float s = fcb[n];
#pragma unroll 8
  for (int j = 0; j < 256; ++j) s = fmaf(hp[j], wp[j], s);
  out[gid] = s;
}

extern "C" void kernel_launch(void* const* d_in, const int* in_sizes, int n_in,
                              void* d_out, int out_size, void* d_ws, size_t ws_size,
                              hipStream_t stream) {
  const float* x     = (const float*)d_in[0];
  const float* Wih0f = (const float*)d_in[1];
  const float* Whh0f = (const float*)d_in[2];
  const float* b0f   = (const float*)d_in[3];
  const float* Wih0r = (const float*)d_in[4];
  const float* Whh0r = (const float*)d_in[5];
  const float* b0r   = (const float*)d_in[6];
  const float* Wih1f = (const float*)d_in[7];
  const float* Whh1f = (const float*)d_in[8];
  const float* b1f   = (const float*)d_in[9];
  const float* Wih1r = (const float*)d_in[10];
  const float* Whh1r = (const float*)d_in[11];
  const float* b1r   = (const float*)d_in[12];
  const float* fcw   = (const float*)d_in[13];
  const float* fcb   = (const float*)d_in[14];

  short* h1 = (short*)d_ws;                                        // 64MB
  float* h2last = (float*)((char*)d_ws + (64ull << 20));           // 256KB
  float* cstate = (float*)((char*)d_ws + (64ull << 20) + (512ull << 10));  // 256KB
  int* hstate = (int*)((char*)d_ws + (64ull << 20) + (768ull << 10));      // 256KB
  short* pre = (short*)((char*)d_ws + (66ull << 20));

  // chunk: per-t pre bytes = 2*16*8*1024*2 = 512KB
  size_t budget = ws_size > (66ull << 20) ? ws_size - (66ull << 20) : 0;
  int chunkT = 0;
  const int cands[7] = {512, 256, 128, 64, 32, 16, 8};
  for (int i = 0; i < 7; ++i)
    if ((size_t)cands[i] * (512ull << 10) <= budget) { chunkT = cands[i]; break; }

  rec0c4<<<dim3(128), dim3(512), 0, stream>>>(
      x, Wih0f, Whh0f, b0f, Wih0r, Whh0r, b0r, h1);

  if (chunkT > 0) {
    for (int cs = 0; cs < TT; cs += chunkT) {
      pre1<<<dim3(4 * chunkT), dim3(512), 0, stream>>>(
          h1, Wih1f, b1f, Wih1r, b1r, pre, cs, chunkT);
      rec1c4<<<dim3(128), dim3(512), 0, stream>>>(
          pre, Whh1f, Whh1r, h2last, cstate, hstate, cs, chunkT);
    }
  } else {
    rec1_fused<<<dim3(32), dim3(512), 0, stream>>>(
        h1, Wih1f, Whh1f, b1f, Wih1r, Whh1r, b1r, h2last);
  }

  fc_kernel<<<dim3((BB * NCLS + 255) / 256), dim3(256), 0, stream>>>(
      h2last, fcw, fcb, (float*)d_out);
}